// Round 1
// baseline (301.095 us; speedup 1.0000x reference)
//
#include <hip/hip_runtime.h>
#include <hip/hip_bf16.h>

typedef short short8 __attribute__((ext_vector_type(8)));
typedef float f32x4 __attribute__((ext_vector_type(4)));

#define BH_ 64
#define L_ 1024
#define DK_ 64

__device__ __forceinline__ unsigned short f2bf(float f) {
    unsigned int u = __float_as_uint(f);
    u += 0x7FFFu + ((u >> 16) & 1u);
    return (unsigned short)(u >> 16);
}
__device__ __forceinline__ float bf2f(unsigned short h) {
    return __uint_as_float(((unsigned int)h) << 16);
}

// ---------------- prep: K -> Khi/Klo bf16 (hi/lo split) ----------------
__global__ void prep_k(const float* __restrict__ K,
                       unsigned short* __restrict__ Khi,
                       unsigned short* __restrict__ Klo) {
    int idx = blockIdx.x * 256 + threadIdx.x;  // one float4, grid sized exactly
    float4 v = reinterpret_cast<const float4*>(K)[idx];
    float f[4] = {v.x, v.y, v.z, v.w};
    ushort4 hi, lo;
    unsigned short h;
    h = f2bf(f[0]); hi.x = h; lo.x = f2bf(f[0] - bf2f(h));
    h = f2bf(f[1]); hi.y = h; lo.y = f2bf(f[1] - bf2f(h));
    h = f2bf(f[2]); hi.z = h; lo.z = f2bf(f[2] - bf2f(h));
    h = f2bf(f[3]); hi.w = h; lo.w = f2bf(f[3] - bf2f(h));
    reinterpret_cast<ushort4*>(Khi)[idx] = hi;
    reinterpret_cast<ushort4*>(Klo)[idx] = lo;
}

// ---------------- prep: V -> Vt bf16 transposed [bh][n][k] ----------------
__global__ void prep_v(const float* __restrict__ V, unsigned short* __restrict__ Vt) {
    __shared__ float lds[64][65];
    int bh = blockIdx.x >> 4, kt = blockIdx.x & 15;
    int t = threadIdx.x;
    const float* Vb = V + ((size_t)bh * L_ + kt * 64) * DK_;
#pragma unroll
    for (int it = 0; it < 4; ++it) {
        int idx = it * 256 + t;          // 1024 float4 = 64x64 tile
        int row = idx >> 4, c4 = idx & 15;
        float4 v = reinterpret_cast<const float4*>(Vb + (size_t)row * DK_)[c4];
        lds[row][c4 * 4 + 0] = v.x; lds[row][c4 * 4 + 1] = v.y;
        lds[row][c4 * 4 + 2] = v.z; lds[row][c4 * 4 + 3] = v.w;
    }
    __syncthreads();
    unsigned short* Vtb = Vt + (size_t)bh * 64 * L_ + kt * 64;
#pragma unroll
    for (int it = 0; it < 4; ++it) {
        int idx = it * 256 + t;
        int n = idx >> 4, c4 = idx & 15;
        ushort4 o;
        o.x = f2bf(lds[c4 * 4 + 0][n]);
        o.y = f2bf(lds[c4 * 4 + 1][n]);
        o.z = f2bf(lds[c4 * 4 + 2][n]);
        o.w = f2bf(lds[c4 * 4 + 3][n]);
        *reinterpret_cast<ushort4*>(Vtb + (size_t)n * L_ + c4 * 4) = o;
    }
}

// ---------------- main fused attention ----------------
// WG = 16 q-rows, 4 waves; wave w owns k in [w*256, w*256+256).
// S^T tiles via mfma(Kfrag, Qfrag): lane holds q=lane&15, k=k0+4*(lane>>4)+r.
__global__ __launch_bounds__(256, 2) void attn_main(
    const float* __restrict__ Q, const int* __restrict__ mask,
    const unsigned short* __restrict__ Khi, const unsigned short* __restrict__ Klo,
    const unsigned short* __restrict__ Vt,
    float* __restrict__ ctx_out, float* __restrict__ attn_out)
{
    const int qt = blockIdx.x, bh = blockIdx.y;
    const int tid = threadIdx.x;
    const int w = tid >> 6;
    const int lane = tid & 63;
    const int lg = lane >> 4, lr = lane & 15;
    const int q0 = qt * 16;

    __shared__ float red[2][4][16];
    __shared__ float ctxbuf[4][16][68];
    __shared__ unsigned short pbuf[4][16 * 40];

    // Q fragments (B-operand of S^T): lane holds Q[q0+lr][dk = f*32 + lg*8 + j]
    short8 qhi[2], qlo[2];
    {
        const float* qp = Q + ((size_t)bh * L_ + q0 + lr) * DK_ + lg * 8;
#pragma unroll
        for (int f = 0; f < 2; ++f) {
            float4 a = *reinterpret_cast<const float4*>(qp + f * 32);
            float4 b = *reinterpret_cast<const float4*>(qp + f * 32 + 4);
            float fv[8] = {a.x, a.y, a.z, a.w, b.x, b.y, b.z, b.w};
#pragma unroll
            for (int j = 0; j < 8; ++j) {
                unsigned short h = f2bf(fv[j]);
                qhi[f][j] = (short)h;
                qlo[f][j] = (short)f2bf(fv[j] - bf2f(h));
            }
        }
    }

    const size_t rowbase = ((size_t)bh * L_ + q0 + lr) * L_;  // [bh][q][*] for mask/attn

    // ---- QK^T with hi/lo split; scores stay in registers ----
    f32x4 s[16];
#pragma unroll
    for (int tt = 0; tt < 16; ++tt) {
        const int k0 = w * 256 + tt * 16;
        const unsigned short* kp = Khi + ((size_t)bh * L_ + k0 + lr) * DK_ + lg * 8;
        const unsigned short* kq = Klo + ((size_t)bh * L_ + k0 + lr) * DK_ + lg * 8;
        short8 kh0 = *reinterpret_cast<const short8*>(kp);
        short8 kh1 = *reinterpret_cast<const short8*>(kp + 32);
        short8 kl0 = *reinterpret_cast<const short8*>(kq);
        short8 kl1 = *reinterpret_cast<const short8*>(kq + 32);
        f32x4 acc = {0.f, 0.f, 0.f, 0.f};
        acc = __builtin_amdgcn_mfma_f32_16x16x32_bf16(kh0, qhi[0], acc, 0, 0, 0);
        acc = __builtin_amdgcn_mfma_f32_16x16x32_bf16(kh1, qhi[1], acc, 0, 0, 0);
        acc = __builtin_amdgcn_mfma_f32_16x16x32_bf16(kh0, qlo[0], acc, 0, 0, 0);
        acc = __builtin_amdgcn_mfma_f32_16x16x32_bf16(kh1, qlo[1], acc, 0, 0, 0);
        acc = __builtin_amdgcn_mfma_f32_16x16x32_bf16(kl0, qhi[0], acc, 0, 0, 0);
        acc = __builtin_amdgcn_mfma_f32_16x16x32_bf16(kl1, qhi[1], acc, 0, 0, 0);
        int4 mv = *reinterpret_cast<const int4*>(&mask[rowbase + k0 + lg * 4]);
        s[tt][0] = mv.x ? -1e9f : 0.25f * acc[0];
        s[tt][1] = mv.y ? -1e9f : 0.25f * acc[1];
        s[tt][2] = mv.z ? -1e9f : 0.25f * acc[2];
        s[tt][3] = mv.w ? -1e9f : 0.25f * acc[3];
    }

    // ---- softmax: row max ----
    float m = -3.0e38f;
#pragma unroll
    for (int tt = 0; tt < 16; ++tt)
        m = fmaxf(m, fmaxf(fmaxf(s[tt][0], s[tt][1]), fmaxf(s[tt][2], s[tt][3])));
    m = fmaxf(m, __shfl_xor(m, 16));
    m = fmaxf(m, __shfl_xor(m, 32));
    if (lane < 16) red[0][w][lr] = m;
    __syncthreads();
    float gm = fmaxf(fmaxf(red[0][0][lr], red[0][1][lr]),
                     fmaxf(red[0][2][lr], red[0][3][lr]));

    // ---- exp + row sum (overwrite s with p) ----
    float lsum = 0.f;
#pragma unroll
    for (int tt = 0; tt < 16; ++tt) {
#pragma unroll
        for (int r = 0; r < 4; ++r) {
            float p = __expf(s[tt][r] - gm);
            s[tt][r] = p;
            lsum += p;
        }
    }
    lsum += __shfl_xor(lsum, 16);
    lsum += __shfl_xor(lsum, 32);
    if (lane < 16) red[1][w][lr] = lsum;
    __syncthreads();
    float gsum = red[1][0][lr] + red[1][1][lr] + red[1][2][lr] + red[1][3][lr];
    float rinv = 1.0f / gsum;

    // ---- attn write + PV (per-wave LDS bounce to A-frag layout) ----
    f32x4 cacc[4] = {{0,0,0,0},{0,0,0,0},{0,0,0,0},{0,0,0,0}};
    unsigned short* pb = &pbuf[w][0];
#pragma unroll
    for (int c = 0; c < 8; ++c) {
#pragma unroll
        for (int t2 = 0; t2 < 2; ++t2) {
            const int tt = 2 * c + t2;
            const int k0 = w * 256 + tt * 16;
            float4 pv;
            pv.x = s[tt][0] * rinv; pv.y = s[tt][1] * rinv;
            pv.z = s[tt][2] * rinv; pv.w = s[tt][3] * rinv;
            *reinterpret_cast<float4*>(&attn_out[rowbase + k0 + lg * 4]) = pv;
            ushort4 pb4;
            pb4.x = f2bf(pv.x); pb4.y = f2bf(pv.y);
            pb4.z = f2bf(pv.z); pb4.w = f2bf(pv.w);
            *reinterpret_cast<ushort4*>(&pb[lr * 40 + t2 * 16 + lg * 4]) = pb4;
        }
        // A-frag read: p[q=lr][krel = lg*8 + j]  (wave-private LDS, in-order)
        short8 pa = *reinterpret_cast<const short8*>(&pb[lr * 40 + lg * 8]);
#pragma unroll
        for (int nt = 0; nt < 4; ++nt) {
            const unsigned short* vp = Vt + ((size_t)bh * 64 + nt * 16 + lr) * L_
                                          + w * 256 + c * 32 + lg * 8;
            short8 vb = *reinterpret_cast<const short8*>(vp);
            cacc[nt] = __builtin_amdgcn_mfma_f32_16x16x32_bf16(pa, vb, cacc[nt], 0, 0, 0);
        }
    }

    // ---- combine partial contexts across waves ----
#pragma unroll
    for (int nt = 0; nt < 4; ++nt)
#pragma unroll
        for (int r = 0; r < 4; ++r)
            ctxbuf[w][lg * 4 + r][nt * 16 + lr] = cacc[nt][r];
    __syncthreads();
    {
        int e = tid * 4;
        int q = e >> 6, n = e & 63;
        float4 a0 = *reinterpret_cast<float4*>(&ctxbuf[0][q][n]);
        float4 a1 = *reinterpret_cast<float4*>(&ctxbuf[1][q][n]);
        float4 a2 = *reinterpret_cast<float4*>(&ctxbuf[2][q][n]);
        float4 a3 = *reinterpret_cast<float4*>(&ctxbuf[3][q][n]);
        float4 o;
        o.x = a0.x + a1.x + a2.x + a3.x;
        o.y = a0.y + a1.y + a2.y + a3.y;
        o.z = a0.z + a1.z + a2.z + a3.z;
        o.w = a0.w + a1.w + a2.w + a3.w;
        *reinterpret_cast<float4*>(&ctx_out[((size_t)bh * L_ + q0 + q) * DK_ + n]) = o;
    }
}

extern "C" void kernel_launch(void* const* d_in, const int* in_sizes, int n_in,
                              void* d_out, int out_size, void* d_ws, size_t ws_size,
                              hipStream_t stream) {
    const float* Q = (const float*)d_in[0];
    const float* K = (const float*)d_in[1];
    const float* V = (const float*)d_in[2];
    const int* mask = (const int*)d_in[3];
    float* ctx_out = (float*)d_out;
    float* attn_out = ctx_out + (size_t)BH_ * L_ * DK_;

    unsigned short* Khi = (unsigned short*)d_ws;
    unsigned short* Klo = Khi + (size_t)BH_ * L_ * DK_;
    unsigned short* Vt  = Klo + (size_t)BH_ * L_ * DK_;

    hipLaunchKernelGGL(prep_k, dim3(4096), dim3(256), 0, stream, K, Khi, Klo);
    hipLaunchKernelGGL(prep_v, dim3(1024), dim3(256), 0, stream, V, Vt);
    hipLaunchKernelGGL(attn_main, dim3(64, 64), dim3(256), 0, stream,
                       Q, mask, Khi, Klo, Vt, ctx_out, attn_out);
}

// Round 3
// 263.931 us; speedup vs baseline: 1.1408x; 1.1408x over previous
//
#include <hip/hip_runtime.h>
#include <hip/hip_bf16.h>

typedef _Float16 half8 __attribute__((ext_vector_type(8)));
typedef _Float16 half2v __attribute__((ext_vector_type(2)));
typedef __fp16 fp16x2 __attribute__((ext_vector_type(2)));
typedef float f32x4 __attribute__((ext_vector_type(4)));

#define BH_ 64
#define L_ 1024
#define DK_ 64

__device__ __forceinline__ unsigned short f2h(float f) {
    _Float16 h = (_Float16)f;
    return __builtin_bit_cast(unsigned short, h);
}
__device__ __forceinline__ unsigned int pk2h(float a, float b) {
    fp16x2 h = __builtin_amdgcn_cvt_pkrtz(a, b);
    return __builtin_bit_cast(unsigned int, h);
}

// ---------------- prep: K -> fp16 ----------------
__global__ void prep_k(const float* __restrict__ K, unsigned short* __restrict__ Kh) {
    int idx = blockIdx.x * 256 + threadIdx.x;  // one float4 each; grid sized exactly
    float4 v = reinterpret_cast<const float4*>(K)[idx];
    ushort4 o;
    o.x = f2h(v.x); o.y = f2h(v.y); o.z = f2h(v.z); o.w = f2h(v.w);
    reinterpret_cast<ushort4*>(Kh)[idx] = o;
}

// ---------------- prep: V -> Vt fp16 transposed [bh][n][k] ----------------
__global__ void prep_v(const float* __restrict__ V, unsigned short* __restrict__ Vt) {
    __shared__ float lds[64][65];
    int bh = blockIdx.x >> 4, kt = blockIdx.x & 15;
    int t = threadIdx.x;
    const float* Vb = V + ((size_t)bh * L_ + kt * 64) * DK_;
#pragma unroll
    for (int it = 0; it < 4; ++it) {
        int idx = it * 256 + t;  // 1024 float4 = 64x64 tile
        int row = idx >> 4, c4 = idx & 15;
        float4 v = reinterpret_cast<const float4*>(Vb + (size_t)row * DK_)[c4];
        lds[row][c4 * 4 + 0] = v.x; lds[row][c4 * 4 + 1] = v.y;
        lds[row][c4 * 4 + 2] = v.z; lds[row][c4 * 4 + 3] = v.w;
    }
    __syncthreads();
    unsigned short* Vtb = Vt + (size_t)bh * 64 * L_ + kt * 64;
#pragma unroll
    for (int it = 0; it < 4; ++it) {
        int idx = it * 256 + t;
        int n = idx >> 4, c4 = idx & 15;
        ushort4 o;
        o.x = f2h(lds[c4 * 4 + 0][n]);
        o.y = f2h(lds[c4 * 4 + 1][n]);
        o.z = f2h(lds[c4 * 4 + 2][n]);
        o.w = f2h(lds[c4 * 4 + 3][n]);
        *reinterpret_cast<ushort4*>(Vtb + (size_t)n * L_ + c4 * 4) = o;
    }
}

// ---------------- main fused attention ----------------
// WG = 16 q-rows, 4 waves; wave w owns k in [w*256, w*256+256).
// S^T tiles via mfma(Kfrag, Qfrag): lane holds q=lane&15, k=k0+4*(lane>>4)+r.
// Scores packed fp16 (2 u32/tile); masked = -inf; PV unnormalized, ctx scaled in epilogue.
__global__ __launch_bounds__(256, 5) void attn_main(
    const float* __restrict__ Q, const int* __restrict__ mask,
    const unsigned short* __restrict__ Kh, const unsigned short* __restrict__ Vt,
    float* __restrict__ ctx_out, float* __restrict__ attn_out)
{
    const int qt = blockIdx.x, bh = blockIdx.y;
    const int tid = threadIdx.x;
    const int w = tid >> 6;
    const int lane = tid & 63;
    const int lg = lane >> 4, lr = lane & 15;
    const int q0 = qt * 16;

    __shared__ float red[2][4][16];
    __shared__ float ctxbuf[4][16][68];
    __shared__ unsigned short pbuf[4][640];

    // Q B-frag: lane holds Q[q0+lr][f*32 + lg*8 + j], fp16
    half8 qh[2];
    {
        const float* qp = Q + ((size_t)bh * L_ + q0 + lr) * DK_ + lg * 8;
#pragma unroll
        for (int f = 0; f < 2; ++f) {
            float4 a = *reinterpret_cast<const float4*>(qp + f * 32);
            float4 b = *reinterpret_cast<const float4*>(qp + f * 32 + 4);
            qh[f][0] = (_Float16)a.x; qh[f][1] = (_Float16)a.y;
            qh[f][2] = (_Float16)a.z; qh[f][3] = (_Float16)a.w;
            qh[f][4] = (_Float16)b.x; qh[f][5] = (_Float16)b.y;
            qh[f][6] = (_Float16)b.z; qh[f][7] = (_Float16)b.w;
        }
    }

    const size_t rowbase = ((size_t)bh * L_ + q0 + lr) * L_;  // [bh][q][*] mask/attn row
    const unsigned short* kp = Kh + ((size_t)bh * L_ + w * 256 + lr) * DK_ + lg * 8;
    const int* mp = mask + rowbase + w * 256 + lg * 4;

    // ---- QK^T: scores packed fp16, software-pipelined (K depth-1, mask depth-2) ----
    unsigned int sh[16][2];
    float mx = -INFINITY;

    half8 kc0 = *reinterpret_cast<const half8*>(kp);
    half8 kc1 = *reinterpret_cast<const half8*>(kp + 32);
    int4 m0 = *reinterpret_cast<const int4*>(mp);
    int4 m1 = *reinterpret_cast<const int4*>(mp + 16);

#pragma unroll
    for (int tt = 0; tt < 16; ++tt) {
        half8 kn0 = kc0, kn1 = kc1;
        int4 mn = m1;
        if (tt < 15) {
            kn0 = *reinterpret_cast<const half8*>(kp + (tt + 1) * 1024);
            kn1 = *reinterpret_cast<const half8*>(kp + (tt + 1) * 1024 + 32);
        }
        if (tt < 14) mn = *reinterpret_cast<const int4*>(mp + (tt + 2) * 16);
        f32x4 acc = {0.f, 0.f, 0.f, 0.f};
        acc = __builtin_amdgcn_mfma_f32_16x16x32_f16(kc0, qh[0], acc, 0, 0, 0);
        acc = __builtin_amdgcn_mfma_f32_16x16x32_f16(kc1, qh[1], acc, 0, 0, 0);
        float s0 = m0.x ? -INFINITY : 0.25f * acc[0];
        float s1 = m0.y ? -INFINITY : 0.25f * acc[1];
        float s2 = m0.z ? -INFINITY : 0.25f * acc[2];
        float s3 = m0.w ? -INFINITY : 0.25f * acc[3];
        sh[tt][0] = pk2h(s0, s1);
        sh[tt][1] = pk2h(s2, s3);
        mx = fmaxf(mx, fmaxf(fmaxf(s0, s1), fmaxf(s2, s3)));
        kc0 = kn0; kc1 = kn1; m0 = m1; m1 = mn;
    }

    // ---- softmax: row max across lg groups, then across waves ----
    mx = fmaxf(mx, __shfl_xor(mx, 16));
    mx = fmaxf(mx, __shfl_xor(mx, 32));
    if (lane < 16) red[0][w][lr] = mx;
    __syncthreads();
    const float gm = fmaxf(fmaxf(red[0][0][lr], red[0][1][lr]),
                           fmaxf(red[0][2][lr], red[0][3][lr]));

    // ---- exp + row sum; p stays packed fp16 (unnormalized) ----
    float lsum = 0.f;
#pragma unroll
    for (int tt = 0; tt < 16; ++tt) {
        half2v a = __builtin_bit_cast(half2v, sh[tt][0]);
        half2v b = __builtin_bit_cast(half2v, sh[tt][1]);
        float p0 = __expf((float)a[0] - gm);
        float p1 = __expf((float)a[1] - gm);
        float p2 = __expf((float)b[0] - gm);
        float p3 = __expf((float)b[1] - gm);
        lsum += (p0 + p1) + (p2 + p3);
        sh[tt][0] = pk2h(p0, p1);
        sh[tt][1] = pk2h(p2, p3);
    }
    lsum += __shfl_xor(lsum, 16);
    lsum += __shfl_xor(lsum, 32);
    if (lane < 16) red[1][w][lr] = lsum;
    __syncthreads();
    const float gsum = red[1][0][lr] + red[1][1][lr] + red[1][2][lr] + red[1][3][lr];
    const float rinv = 1.0f / gsum;

    // ---- attn write (normalized) + PV (unnormalized p, per-wave LDS bounce) ----
    f32x4 cacc[4] = {{0,0,0,0},{0,0,0,0},{0,0,0,0},{0,0,0,0}};
    unsigned short* pb = &pbuf[w][0];
    const unsigned short* vp = Vt + ((size_t)bh * 64 + lr) * L_ + w * 256 + lg * 8;

    half8 vb0 = *reinterpret_cast<const half8*>(vp);
    half8 vb1 = *reinterpret_cast<const half8*>(vp + 16384);
    half8 vb2 = *reinterpret_cast<const half8*>(vp + 32768);
    half8 vb3 = *reinterpret_cast<const half8*>(vp + 49152);

#pragma unroll
    for (int c = 0; c < 8; ++c) {
        half8 vn0 = vb0, vn1 = vb1, vn2 = vb2, vn3 = vb3;
        if (c < 7) {
            vn0 = *reinterpret_cast<const half8*>(vp + (c + 1) * 32);
            vn1 = *reinterpret_cast<const half8*>(vp + 16384 + (c + 1) * 32);
            vn2 = *reinterpret_cast<const half8*>(vp + 32768 + (c + 1) * 32);
            vn3 = *reinterpret_cast<const half8*>(vp + 49152 + (c + 1) * 32);
        }
#pragma unroll
        for (int t2 = 0; t2 < 2; ++t2) {
            const int tt = 2 * c + t2;
            uint2 pr; pr.x = sh[tt][0]; pr.y = sh[tt][1];
            *reinterpret_cast<uint2*>(&pb[lr * 40 + t2 * 16 + lg * 4]) = pr;
            half2v a = __builtin_bit_cast(half2v, sh[tt][0]);
            half2v b = __builtin_bit_cast(half2v, sh[tt][1]);
            float4 av;
            av.x = (float)a[0] * rinv; av.y = (float)a[1] * rinv;
            av.z = (float)b[0] * rinv; av.w = (float)b[1] * rinv;
            *reinterpret_cast<float4*>(&attn_out[rowbase + w * 256 + tt * 16 + lg * 4]) = av;
        }
        // A-frag read: p[q=lr][k32 = lg*8 + j] (wave-private LDS, in-order)
        half8 pa = *reinterpret_cast<const half8*>(&pb[lr * 40 + lg * 8]);
        cacc[0] = __builtin_amdgcn_mfma_f32_16x16x32_f16(pa, vb0, cacc[0], 0, 0, 0);
        cacc[1] = __builtin_amdgcn_mfma_f32_16x16x32_f16(pa, vb1, cacc[1], 0, 0, 0);
        cacc[2] = __builtin_amdgcn_mfma_f32_16x16x32_f16(pa, vb2, cacc[2], 0, 0, 0);
        cacc[3] = __builtin_amdgcn_mfma_f32_16x16x32_f16(pa, vb3, cacc[3], 0, 0, 0);
        vb0 = vn0; vb1 = vn1; vb2 = vn2; vb3 = vn3;
    }

    // ---- combine partial contexts across waves, normalize by 1/sum ----
#pragma unroll
    for (int nt = 0; nt < 4; ++nt)
#pragma unroll
        for (int r = 0; r < 4; ++r)
            ctxbuf[w][lg * 4 + r][nt * 16 + lr] = cacc[nt][r];
    __syncthreads();
    {
        int e = tid * 4;
        int q = e >> 6, n = e & 63;
        float gs = red[1][0][q] + red[1][1][q] + red[1][2][q] + red[1][3][q];
        float rq = 1.0f / gs;
        float4 a0 = *reinterpret_cast<float4*>(&ctxbuf[0][q][n]);
        float4 a1 = *reinterpret_cast<float4*>(&ctxbuf[1][q][n]);
        float4 a2 = *reinterpret_cast<float4*>(&ctxbuf[2][q][n]);
        float4 a3 = *reinterpret_cast<float4*>(&ctxbuf[3][q][n]);
        float4 o;
        o.x = (a0.x + a1.x + a2.x + a3.x) * rq;
        o.y = (a0.y + a1.y + a2.y + a3.y) * rq;
        o.z = (a0.z + a1.z + a2.z + a3.z) * rq;
        o.w = (a0.w + a1.w + a2.w + a3.w) * rq;
        *reinterpret_cast<float4*>(&ctx_out[((size_t)bh * L_ + q0 + q) * DK_ + n]) = o;
    }
}

extern "C" void kernel_launch(void* const* d_in, const int* in_sizes, int n_in,
                              void* d_out, int out_size, void* d_ws, size_t ws_size,
                              hipStream_t stream) {
    const float* Q = (const float*)d_in[0];
    const float* K = (const float*)d_in[1];
    const float* V = (const float*)d_in[2];
    const int* mask = (const int*)d_in[3];
    float* ctx_out = (float*)d_out;
    float* attn_out = ctx_out + (size_t)BH_ * L_ * DK_;

    unsigned short* Kh = (unsigned short*)d_ws;
    unsigned short* Vt = Kh + (size_t)BH_ * L_ * DK_;

    hipLaunchKernelGGL(prep_k, dim3(4096), dim3(256), 0, stream, K, Kh);
    hipLaunchKernelGGL(prep_v, dim3(1024), dim3(256), 0, stream, V, Vt);
    hipLaunchKernelGGL(attn_main, dim3(64, 64), dim3(256), 0, stream,
                       Q, mask, Kh, Vt, ctx_out, attn_out);
}